// Round 2
// baseline (434.251 us; speedup 1.0000x reference)
//
#include <hip/hip_runtime.h>

// EEBasis (all float32, per reference):
//   out[n, s] = exp(-|zeta[s]| * sqrt(diffs[n, center_idxs[s], 3]))
// N = 262144 rows, 64 centers x float4 (dx,dy,dz,d2), 256 shells.
// Streaming: 256 MiB read + 256 MiB write -> memory-bound, ~81 us floor.
//
// One wave per row: lane j loads center j's float4 (coalesced), r = sqrt(d2),
// shells 4j..4j+3 pull r[center] cross-lane via __shfl (general in
// center_idxs; identity shuffle under the repeat(arange(64),4) structure).

__global__ __launch_bounds__(256) void ee_basis_kernel(
    const float4* __restrict__ diffs,   // [N*64] float4
    const float*  __restrict__ zetas,   // [256]
    const int*    __restrict__ cidx,    // [256]
    float4*       __restrict__ out,     // [N*64] float4 (= [N,256] floats)
    int nrows)
{
    const int tid   = blockIdx.x * blockDim.x + threadIdx.x;
    const int lane  = threadIdx.x & 63;          // = center this lane loads
    const int wave  = tid >> 6;                  // global wave id = row id
    const int waves = (gridDim.x * blockDim.x) >> 6;

    // Loop-invariant per-lane constants for shells 4*lane .. 4*lane+3.
    // zetas/cidx are 1 KiB each -> L1-resident after first touch.
    const int s0 = lane << 2;
    float nb[4]; int c[4];
    #pragma unroll
    for (int k = 0; k < 4; ++k) {
        nb[k] = -fabsf(zetas[s0 + k]) * 1.4426950408889634f;  // -|z|*log2(e)
        c[k]  = cidx[s0 + k];                                  // in [0, 64)
    }

    for (int n = wave; n < nrows; n += waves) {
        const float4 d = diffs[(size_t)n * 64 + lane];
        const float  r = sqrtf(d.w);

        float4 o;
        o.x = exp2f(nb[0] * __shfl(r, c[0], 64));
        o.y = exp2f(nb[1] * __shfl(r, c[1], 64));
        o.z = exp2f(nb[2] * __shfl(r, c[2], 64));
        o.w = exp2f(nb[3] * __shfl(r, c[3], 64));

        out[(size_t)n * 64 + lane] = o;   // shells 4*lane .. 4*lane+3
    }
}

extern "C" void kernel_launch(void* const* d_in, const int* in_sizes, int n_in,
                              void* d_out, int out_size, void* d_ws, size_t ws_size,
                              hipStream_t stream) {
    const float4* diffs = (const float4*)d_in[0];
    const float*  zetas = (const float*)d_in[1];
    const int*    cidx  = (const int*)d_in[2];
    float4*       out   = (float4*)d_out;

    const int nrows = in_sizes[0] / 256;   // [N, 64, 4] floats -> N
    const int block = 256;                 // 4 waves/block -> 4 rows/iter
    const int grid  = 2048;                // 8192 waves, 32 rows each
    ee_basis_kernel<<<grid, block, 0, stream>>>(diffs, zetas, cidx, out, nrows);
}